// Round 1
// 506.544 us; speedup vs baseline: 1.0102x; 1.0102x over previous
//
#include <hip/hip_runtime.h>

// DenseGrid trilinear interpolation, MI355X.
// R3: locality sort. The R2 kernel is 6x over HBM-compulsory traffic because
// uniform-random points gather random 128B lines across the 151 MB codebook
// (random-line HBM regime ~47% of peak). Fix: exact counting sort of points
// into 512 spatial bins (z-plane x y-quadrant), then run the interpolation in
// bin order. Concurrent gather window becomes ~600 KB (L2-resident); codebook
// is swept from HBM ~once. Per-point math is bit-identical (same fma chains),
// output scattered back to original index -> absmax unchanged.
//
// Pipeline: k_zero -> k_hist -> k_scan -> k_scatter -> k_main.
// Falls back to the R2 single-kernel path if ws_size is too small.

constexpr int RES = 128;
constexpr int NB  = 512;            // bins: iz0 * 4 + (iy0 >> 5)
constexpr int TPB = 576;            // main kernel: 9 threads/point, 64 pts/block
constexpr int PPB = TPB / 9;

constexpr int HIST_CHUNK = 1024;    // points per block in k_hist
constexpr int SCAT_CHUNK = 4096;    // points per block in k_scatter

typedef float vf2 __attribute__((ext_vector_type(2)));
typedef float vf4 __attribute__((ext_vector_type(4)));

struct Xf {
    float m00, m01, m02, m10, m11, m12, m20, m21, m22;
    float tx, ty, tz;
};

__device__ __forceinline__ Xf load_xf(const float* __restrict__ tr) {
    Xf X;
    const float a = tr[0], b = tr[1],  c = tr[2];
    const float d = tr[4], e = tr[5],  g = tr[6];
    const float h = tr[8], i = tr[9],  j = tr[10];
    X.tx = tr[3]; X.ty = tr[7]; X.tz = tr[11];
    const float det = a*(e*j - g*i) - b*(d*j - g*h) + c*(d*i - e*h);
    const float rd  = 1.0f / det;
    X.m00 = (e*j - g*i) * rd; X.m01 = (c*i - b*j) * rd; X.m02 = (b*g - c*e) * rd;
    X.m10 = (g*h - d*j) * rd; X.m11 = (a*j - c*h) * rd; X.m12 = (c*d - a*g) * rd;
    X.m20 = (d*i - e*h) * rd; X.m21 = (b*h - a*i) * rd; X.m22 = (a*e - b*d) * rd;
    return X;
}

// Explicit fma chain so the bin computation is bit-identical across kernels
// (hist count MUST match scatter assignment).
__device__ __forceinline__ float qcoord(float m0, float m1, float m2,
                                        float x, float y, float z) {
    return __fmaf_rn(m0, x, __fmaf_rn(m1, y, m2 * z)) * (float)(RES - 1);
}

__device__ __forceinline__ int bin_of(const Xf& X, float x, float y, float z) {
    const float qy = qcoord(X.m10, X.m11, X.m12, x, y, z);
    const float qz = qcoord(X.m20, X.m21, X.m22, x, y, z);
    const int iy0 = min(max((int)floorf(qy), 0), RES - 1);
    const int iz0 = min(max((int)floorf(qz), 0), RES - 1);
    return (iz0 << 2) + (iy0 >> 5);
}

__global__ __launch_bounds__(NB)
void k_zero(unsigned* __restrict__ hist) {
    hist[threadIdx.x] = 0u;
}

__global__ __launch_bounds__(256)
void k_hist(const float* __restrict__ pts, const float* __restrict__ tr,
            unsigned* __restrict__ hist, int npts)
{
    __shared__ unsigned sh[NB];
    for (int b = threadIdx.x; b < NB; b += 256) sh[b] = 0u;
    __syncthreads();
    const Xf X = load_xf(tr);
    const int base = blockIdx.x * HIST_CHUNK;
    #pragma unroll
    for (int i = 0; i < HIST_CHUNK / 256; ++i) {
        const int p = base + threadIdx.x + i * 256;
        if (p < npts) {
            const float x = pts[p*3 + 0] - X.tx;
            const float y = pts[p*3 + 1] - X.ty;
            const float z = pts[p*3 + 2] - X.tz;
            atomicAdd(&sh[bin_of(X, x, y, z)], 1u);
        }
    }
    __syncthreads();
    for (int b = threadIdx.x; b < NB; b += 256) {
        const unsigned c = sh[b];
        if (c) atomicAdd(&hist[b], c);
    }
}

__global__ __launch_bounds__(NB)
void k_scan(const unsigned* __restrict__ hist, unsigned* __restrict__ cursor)
{
    __shared__ unsigned s[NB];
    const int t = threadIdx.x;
    const unsigned my = hist[t];
    s[t] = my;
    __syncthreads();
    for (int off = 1; off < NB; off <<= 1) {
        const unsigned v = (t >= off) ? s[t - off] : 0u;
        __syncthreads();
        s[t] += v;
        __syncthreads();
    }
    cursor[t] = s[t] - my;   // exclusive prefix sum
}

__global__ __launch_bounds__(256)
void k_scatter(const float* __restrict__ pts, const float* __restrict__ tr,
               unsigned* __restrict__ cursor, vf4* __restrict__ rec, int npts)
{
    __shared__ unsigned shist[NB], sbase[NB], scur[NB];
    const int t = threadIdx.x;
    for (int b = t; b < NB; b += 256) { shist[b] = 0u; scur[b] = 0u; }
    __syncthreads();
    const Xf X = load_xf(tr);
    const int base = blockIdx.x * SCAT_CHUNK;
    #pragma unroll
    for (int i = 0; i < SCAT_CHUNK / 256; ++i) {
        const int p = base + t + i * 256;
        if (p < npts) {
            const float x = pts[p*3 + 0] - X.tx;
            const float y = pts[p*3 + 1] - X.ty;
            const float z = pts[p*3 + 2] - X.tz;
            atomicAdd(&shist[bin_of(X, x, y, z)], 1u);
        }
    }
    __syncthreads();
    for (int b = t; b < NB; b += 256)
        sbase[b] = atomicAdd(&cursor[b], shist[b]);
    __syncthreads();
    #pragma unroll
    for (int i = 0; i < SCAT_CHUNK / 256; ++i) {
        const int p = base + t + i * 256;
        if (p < npts) {
            const float x = pts[p*3 + 0] - X.tx;
            const float y = pts[p*3 + 1] - X.ty;
            const float z = pts[p*3 + 2] - X.tz;
            const float qx = qcoord(X.m00, X.m01, X.m02, x, y, z);
            const float qy = qcoord(X.m10, X.m11, X.m12, x, y, z);
            const float qz = qcoord(X.m20, X.m21, X.m22, x, y, z);
            const int bn = bin_of(X, x, y, z);
            const unsigned r = atomicAdd(&scur[bn], 1u);
            unsigned pos = sbase[bn] + r;
            if (pos >= (unsigned)npts) pos = (unsigned)npts - 1u;  // insurance only
            vf4 v; v.x = qx; v.y = qy; v.z = qz; v.w = __int_as_float(p);
            rec[pos] = v;
        }
    }
}

__global__ __launch_bounds__(TPB)
void k_main(const vf4* __restrict__ rec, const float* __restrict__ cb,
            float* __restrict__ out, int npts)
{
    __shared__ vf4 srec[PPB];
    if (threadIdx.x < PPB) {
        const int g = blockIdx.x * PPB + threadIdx.x;
        if (g < npts) srec[threadIdx.x] = rec[g];
    }
    __syncthreads();

    const int pl = threadIdx.x / 9;
    const int f  = threadIdx.x - pl * 9;
    const int p  = blockIdx.x * PPB + pl;
    if (p >= npts) return;

    const vf4 r = srec[pl];
    const float qx = r.x, qy = r.y, qz = r.z;
    const int idx = __float_as_int(r.w);

    const float fx = floorf(qx), fy = floorf(qy), fz = floorf(qz);
    const float wx1 = qx - fx, wy1 = qy - fy, wz1 = qz - fz;
    const float wx0 = 1.0f - wx1, wy0 = 1.0f - wy1, wz0 = 1.0f - wz1;
    const int ix0 = min(max((int)fx, 0), RES - 1); const int ix1 = min(ix0 + 1, RES - 1);
    const int iy0 = min(max((int)fy, 0), RES - 1); const int iy1 = min(iy0 + 1, RES - 1);
    const int iz0 = min(max((int)fz, 0), RES - 1); const int iz1 = min(iz0 + 1, RES - 1);

    int   ro[8];
    float w[8];
    #pragma unroll
    for (int k = 0; k < 8; ++k) {
        const int dx = k & 1, dy = (k >> 1) & 1, dz = k >> 2;
        const int ix = dx ? ix1 : ix0;
        const int iy = dy ? iy1 : iy0;
        const int iz = dz ? iz1 : iz0;
        ro[k] = ix + (iy << 7) + (iz << 14);
        w[k]  = (dx ? wx1 : wx0) * (dy ? wy1 : wy0) * (dz ? wz1 : wz0);
    }

    // Cacheable gathers: after the sort these hit L2/L3.
    const float* cbf = cb + 2 * f;
    vf2 v[8];
    #pragma unroll
    for (int k = 0; k < 8; ++k)
        v[k] = *reinterpret_cast<const vf2*>(cbf + ro[k] * 18);

    float ax = 0.0f, ay = 0.0f;
    #pragma unroll
    for (int k = 0; k < 8; ++k) { ax += v[k].x * w[k]; ay += v[k].y * w[k]; }

    // Scattered 72 B/point store to original index; keep it out of L3.
    vf2 o; o.x = ax; o.y = ay;
    __builtin_nontemporal_store(o, reinterpret_cast<vf2*>(out + idx * 18 + 2 * f));
}

// ---------------- R2 fallback (used only if workspace is too small) ----------
__global__ __launch_bounds__(TPB)
void dense_grid_trilerp(const float* __restrict__ pts,
                        const float* __restrict__ cb,
                        const float* __restrict__ tr,
                        float* __restrict__ out,
                        int npts)
{
    __shared__ float spts[PPB * 3];
    if (threadIdx.x < PPB * 3) {
        int g = blockIdx.x * (PPB * 3) + threadIdx.x;
        spts[threadIdx.x] = (g < npts * 3) ? __builtin_nontemporal_load(&pts[g]) : 0.0f;
    }
    __syncthreads();

    const int pl = threadIdx.x / 9;
    const int f  = threadIdx.x - pl * 9;
    const int p  = blockIdx.x * PPB + pl;
    if (p >= npts) return;

    const Xf X = load_xf(tr);
    const float x = spts[pl*3 + 0] - X.tx;
    const float y = spts[pl*3 + 1] - X.ty;
    const float z = spts[pl*3 + 2] - X.tz;
    const float qx = qcoord(X.m00, X.m01, X.m02, x, y, z);
    const float qy = qcoord(X.m10, X.m11, X.m12, x, y, z);
    const float qz = qcoord(X.m20, X.m21, X.m22, x, y, z);

    const float fx = floorf(qx), fy = floorf(qy), fz = floorf(qz);
    const float wx1 = qx - fx, wy1 = qy - fy, wz1 = qz - fz;
    const float wx0 = 1.0f - wx1, wy0 = 1.0f - wy1, wz0 = 1.0f - wz1;
    const int ix0 = min(max((int)fx, 0), RES - 1); const int ix1 = min(ix0 + 1, RES - 1);
    const int iy0 = min(max((int)fy, 0), RES - 1); const int iy1 = min(iy0 + 1, RES - 1);
    const int iz0 = min(max((int)fz, 0), RES - 1); const int iz1 = min(iz0 + 1, RES - 1);

    int   ro[8];
    float w[8];
    #pragma unroll
    for (int k = 0; k < 8; ++k) {
        const int dx = k & 1, dy = (k >> 1) & 1, dz = k >> 2;
        const int ix = dx ? ix1 : ix0;
        const int iy = dy ? iy1 : iy0;
        const int iz = dz ? iz1 : iz0;
        ro[k] = ix + (iy << 7) + (iz << 14);
        w[k]  = (dx ? wx1 : wx0) * (dy ? wy1 : wy0) * (dz ? wz1 : wz0);
    }

    const float* cbf = cb + 2 * f;
    vf2 v[8];
    #pragma unroll
    for (int k = 0; k < 8; ++k)
        v[k] = *reinterpret_cast<const vf2*>(cbf + ro[k] * 18);

    float ax = 0.0f, ay = 0.0f;
    #pragma unroll
    for (int k = 0; k < 8; ++k) { ax += v[k].x * w[k]; ay += v[k].y * w[k]; }

    vf2 o; o.x = ax; o.y = ay;
    __builtin_nontemporal_store(o, reinterpret_cast<vf2*>(out + p * 18 + 2 * f));
}

extern "C" void kernel_launch(void* const* d_in, const int* in_sizes, int n_in,
                              void* d_out, int out_size, void* d_ws, size_t ws_size,
                              hipStream_t stream) {
    const float* pts = (const float*)d_in[0];   // [4*524288, 3] f32
    const float* cb  = (const float*)d_in[1];   // [128^3, 18] f32
    const float* tr  = (const float*)d_in[2];   // [4,4] f32
    float* out = (float*)d_out;                 // [4*524288, 18] f32

    const int npts = in_sizes[0] / 3;

    const size_t need = (size_t)NB * 2 * sizeof(unsigned) + (size_t)npts * 16 + 256;
    if (d_ws == nullptr || ws_size < need || npts <= 0) {
        const int blocks = (npts + PPB - 1) / PPB;
        dense_grid_trilerp<<<blocks, TPB, 0, stream>>>(pts, cb, tr, out, npts);
        return;
    }

    unsigned* hist   = (unsigned*)d_ws;
    unsigned* cursor = hist + NB;
    vf4* rec = (vf4*)((char*)d_ws + ((size_t)NB * 2 * sizeof(unsigned) + 255) / 256 * 256);

    k_zero<<<1, NB, 0, stream>>>(hist);
    k_hist<<<(npts + HIST_CHUNK - 1) / HIST_CHUNK, 256, 0, stream>>>(pts, tr, hist, npts);
    k_scan<<<1, NB, 0, stream>>>(hist, cursor);
    k_scatter<<<(npts + SCAT_CHUNK - 1) / SCAT_CHUNK, 256, 0, stream>>>(pts, tr, cursor, rec, npts);
    k_main<<<(npts + PPB - 1) / PPB, TPB, 0, stream>>>(rec, cb, out, npts);
}